// Round 6
// baseline (660.555 us; speedup 1.0000x reference)
//
#include <hip/hip_runtime.h>
#include <hip/hip_bf16.h>
#include <cstdint>
#include <cstddef>

#define F 128       // feature dim
#define BSH 8       // rows per bucket = 256
#define MAXB 512    // max buckets supported (N <= 131072)
typedef __attribute__((ext_vector_type(8))) short short8;
typedef __attribute__((ext_vector_type(4))) float floatx4;

static __device__ inline float bf2f(unsigned u) {            // u = bf16 in low 16
    return __builtin_bit_cast(float, u << 16);
}
static __device__ inline unsigned short f2bf(float f) {
    return __builtin_bit_cast(unsigned short, __float2bfloat16(f));
}
static __device__ inline unsigned pack2(float a, float b) {  // low = a, high = b
    return ((unsigned)f2bf(b) << 16) | (unsigned)f2bf(a);
}
// bf16 pair -> fp32 pair: lo = u<<16, hi = u & 0xffff0000
static __device__ inline float2 up2(unsigned u) {
    return make_float2(__builtin_bit_cast(float, u << 16),
                       __builtin_bit_cast(float, u & 0xffff0000u));
}
// packed dual fp32 fma: acc = a * b + acc  (V_PK_FMA_F32)
static __device__ inline void pkfma(float2& acc, float2 a, float2 b) {
    asm("v_pk_fma_f32 %0, %1, %2, %0" : "+v"(acc) : "v"(a), "v"(b));
}

// ---------------------------------------------------------------------------
// Fused prep: [0, castBlocks)          cast x fp32 -> P0 bf16
//             [castBlocks, +256)       permute W -> Wp bf16 [o][j*128+f]
//             [castBlocks+256, +256)   coarse per-bucket histogram
// ---------------------------------------------------------------------------
__global__ __launch_bounds__(256) void prep(
    const float4* __restrict__ x, uint2* __restrict__ p0, long long n4,
    const float* __restrict__ W, unsigned short* __restrict__ Wp,
    const int* __restrict__ rows, int* __restrict__ bucketTot, int nE, int nb,
    int castBlocks)
{
    __shared__ int h[MAXB];
    int bid = blockIdx.x;
    if (bid < castBlocks) {
        long long i = (long long)bid * 256 + threadIdx.x;
        if (i < n4) {
            float4 v = x[i];
            p0[i] = make_uint2(pack2(v.x, v.y), pack2(v.z, v.w));
        }
    } else if (bid < castBlocks + 256) {
        int t = (bid - castBlocks) * 256 + threadIdx.x;   // 65536 total
        int o = t >> 9, rem = t & 511;
        int j = rem >> 7, f = rem & 127;
        Wp[t] = f2bf(W[(size_t)o * 512 + f * 4 + j]);
    } else {
        int hb = bid - castBlocks - 256;                  // 0..255
        for (int i = threadIdx.x; i < MAXB; i += 256) h[i] = 0;
        __syncthreads();
        int stride = 256 * 256;
        for (int e = hb * 256 + threadIdx.x; e < nE; e += stride)
            atomicAdd(&h[rows[e] >> BSH], 1);
        __syncthreads();
        for (int i = threadIdx.x; i < nb; i += 256)
            if (h[i]) atomicAdd(&bucketTot[i], h[i]);
    }
}

// ---------------------------------------------------------------------------
// Counting-sort pass 0b: exclusive scan of bucket totals (single block)
// ---------------------------------------------------------------------------
__global__ __launch_bounds__(512) void bucket_scan(
    const int* __restrict__ tot, int* __restrict__ bucketStart,
    int* __restrict__ bucketCur, int nb)
{
    int t = threadIdx.x;
    int orig = (t < nb) ? tot[t] : 0;
    int v = orig;
    int lane = t & 63, wave = t >> 6;
#pragma unroll
    for (int d = 1; d < 64; d <<= 1) {
        int u = __shfl_up(v, d);
        if (lane >= d) v += u;
    }
    __shared__ int ws[8];
    if (lane == 63) ws[wave] = v;
    __syncthreads();
    int add = 0;
    for (int w = 0; w < wave; w++) add += ws[w];
    int excl = v + add - orig;
    if (t < nb) { bucketStart[t] = excl; bucketCur[t] = excl; }
}

// ---------------------------------------------------------------------------
// Counting-sort pass 1: bucket-scatter with per-block LDS histogram + rank.
// ---------------------------------------------------------------------------
__global__ __launch_bounds__(256) void pass1_scatter(
    const int* __restrict__ rows, const int* __restrict__ cols,
    const float* __restrict__ vals, int* __restrict__ bucketCur,
    uint2* __restrict__ tmp, int nE, int nb)
{
    __shared__ int hcnt[MAXB];
    __shared__ int hbase[MAXB];
    int chunk = (nE + gridDim.x - 1) / gridDim.x;
    int e0 = blockIdx.x * chunk;
    int e1 = min(e0 + chunk, nE);

    for (int i = threadIdx.x; i < MAXB; i += 256) hcnt[i] = 0;
    __syncthreads();
    for (int e = e0 + threadIdx.x; e < e1; e += 256)
        atomicAdd(&hcnt[rows[e] >> BSH], 1);
    __syncthreads();
    for (int i = threadIdx.x; i < nb; i += 256) {
        int c = hcnt[i];
        hbase[i] = c ? atomicAdd(&bucketCur[i], c) : 0;
        hcnt[i] = 0;                          // reuse as rank cursor
    }
    __syncthreads();
    for (int e = e0 + threadIdx.x; e < e1; e += 256) {  // chunk re-read is L2-hot
        int r = rows[e];
        int b = r >> BSH;
        int k = atomicAdd(&hcnt[b], 1);
        tmp[hbase[b] + k] = make_uint2(
            ((unsigned)(r & ((1 << BSH) - 1)) << 17) | (unsigned)cols[e],
            __float_as_uint(vals[e]));
    }
}

// ---------------------------------------------------------------------------
// Counting-sort pass 2: one block per bucket -> rowStart/rowEnd + final edges
// ---------------------------------------------------------------------------
__global__ __launch_bounds__(256) void pass2_finalize(
    const uint2* __restrict__ tmp, const int* __restrict__ bucketStart,
    const int* __restrict__ bucketCur, int* __restrict__ rowStart,
    int* __restrict__ rowEnd, int2* __restrict__ edges, int n)
{
    int b = blockIdx.x;
    int base = bucketStart[b], end = bucketCur[b];  // cur==end after pass1
    int r0 = b << BSH;
    int t = threadIdx.x;

    __shared__ int cnt[1 << BSH];
    cnt[t] = 0;
    __syncthreads();
    for (int i = base + t; i < end; i += 256)
        atomicAdd(&cnt[tmp[i].x >> 17], 1);
    __syncthreads();

    int orig = cnt[t];
    int v = orig;
    int lane = t & 63, wave = t >> 6;
#pragma unroll
    for (int d = 1; d < 64; d <<= 1) {
        int u = __shfl_up(v, d);
        if (lane >= d) v += u;
    }
    __shared__ int ws[4];
    if (lane == 63) ws[wave] = v;
    __syncthreads();
    int add = 0;
    for (int w = 0; w < wave; w++) add += ws[w];
    int offs = base + v + add - orig;               // exclusive prefix + base

    int r = r0 + t;
    if (r < n) { rowStart[r] = offs; rowEnd[r] = offs + orig; }
    cnt[t] = offs;                                  // reuse as placement cursor
    __syncthreads();
    for (int i = base + t; i < end; i += 256) {
        uint2 rec = tmp[i];
        int rl = rec.x >> 17;
        int p = atomicAdd(&cnt[rl], 1);
        edges[p] = make_int2((int)(rec.x & 0x1FFFF), (int)rec.y);
    }
}

// ---------------------------------------------------------------------------
// bf16 gather SpMM + fused Chebyshev epilogue:
//   y[row,:] = bf16( scale * sum_e val_e * x[col_e,:] + beta * prev[row,:] )
// wave64 per row; group g=lane>>4 handles edges i+4u+g (u=0..7); lane l
// loads bf16x8 (16B). 8 gathers in flight per lane (32 edges per wave-iter).
// Accumulate via v_pk_fma_f32 (3 VALU per bf16 pair). fp32 accum; cross-group
// reduce via shfl_xor(16,32).
// ---------------------------------------------------------------------------
__global__ __launch_bounds__(256) void spmm_bf16(
    const int* __restrict__ rowStart, const int* __restrict__ rowEnd,
    const int2* __restrict__ edges, const unsigned short* __restrict__ xb,
    const unsigned short* __restrict__ prevb, unsigned short* __restrict__ yb,
    float scale, float beta, int n)
{
    int row = blockIdx.x * 4 + (threadIdx.x >> 6);
    if (row >= n) return;
    int lane = threadIdx.x & 63;
    int g = lane >> 4, l = lane & 15;

    int s = rowStart[row];
    int c = rowEnd[row] - s;

    float2 acc[4];
#pragma unroll
    for (int j = 0; j < 4; j++) acc[j] = make_float2(0.f, 0.f);

    for (int i = 0; i < c; i += 32) {
        uint4 w[8];
        float v[8];
#pragma unroll
        for (int u = 0; u < 8; u++) {
            int ii = i + u * 4 + g;
            bool ok = ii < c;
            int2 e = edges[s + (ok ? ii : 0)];
            w[u] = *(const uint4*)(xb + (size_t)e.x * F + l * 8);
            v[u] = ok ? __int_as_float(e.y) : 0.f;
        }
#pragma unroll
        for (int u = 0; u < 8; u++) {
            float2 vv = make_float2(v[u], v[u]);
            pkfma(acc[0], up2(w[u].x), vv);
            pkfma(acc[1], up2(w[u].y), vv);
            pkfma(acc[2], up2(w[u].z), vv);
            pkfma(acc[3], up2(w[u].w), vv);
        }
    }

#pragma unroll
    for (int j = 0; j < 4; j++) {
        acc[j].x += __shfl_xor(acc[j].x, 16);
        acc[j].y += __shfl_xor(acc[j].y, 16);
        acc[j].x += __shfl_xor(acc[j].x, 32);
        acc[j].y += __shfl_xor(acc[j].y, 32);
    }

    if (g == 0) {
        float2 r[4];
#pragma unroll
        for (int j = 0; j < 4; j++)
            r[j] = make_float2(scale * acc[j].x, scale * acc[j].y);
        if (beta != 0.f) {
            uint4 p = *(const uint4*)(prevb + (size_t)row * F + l * 8);
            float2 p0 = up2(p.x), p1 = up2(p.y), p2 = up2(p.z), p3 = up2(p.w);
            r[0].x += beta * p0.x; r[0].y += beta * p0.y;
            r[1].x += beta * p1.x; r[1].y += beta * p1.y;
            r[2].x += beta * p2.x; r[2].y += beta * p2.y;
            r[3].x += beta * p3.x; r[3].y += beta * p3.y;
        }
        uint4 o;
        o.x = pack2(r[0].x, r[0].y); o.y = pack2(r[1].x, r[1].y);
        o.z = pack2(r[2].x, r[2].y); o.w = pack2(r[3].x, r[3].y);
        *(uint4*)(yb + (size_t)row * F + l * 8) = o;
    }
}

// ---------------------------------------------------------------------------
// out[N,128] = cheb[N,512](bf16 planes) @ Wp^T + bias, MFMA 16x16x32.
// Register-resident B: wave w owns col-tiles nt={2w,2w+1}, preloads its 32
// B-frags ONCE, grid-strides over 16-row M-tiles.
// ---------------------------------------------------------------------------
__global__ __launch_bounds__(256) void gemm_mfma(
    const unsigned short* __restrict__ Tb, const unsigned short* __restrict__ Wp,
    const float* __restrict__ bias, float* __restrict__ out, int n, int nTiles)
{
    int wave = threadIdx.x >> 6, lane = threadIdx.x & 63;
    int l15 = lane & 15, quad = lane >> 4;
    size_t planeStride = (size_t)n * F;

    short8 bfr[2][16];
    float bv[2];
#pragma unroll
    for (int nt = 0; nt < 2; nt++) {
        int col = (wave * 2 + nt) * 16 + l15;
        bv[nt] = bias[col];
        const unsigned short* bp = Wp + ((size_t)col << 9) + quad * 8;
#pragma unroll
        for (int kk = 0; kk < 16; kk++)
            bfr[nt][kk] = __builtin_bit_cast(short8, *(const uint4*)(bp + kk * 32));
    }

    for (int tile = blockIdx.x; tile < nTiles; tile += gridDim.x) {
        int m0 = tile * 16;
        int m = m0 + l15;
        int mc = m < n ? m : n - 1;

        short8 a[16];
#pragma unroll
        for (int kk = 0; kk < 16; kk++) {
            const unsigned short* ap = Tb + (size_t)(kk >> 2) * planeStride
                                     + (size_t)mc * F + (kk & 3) * 32 + quad * 8;
            a[kk] = __builtin_bit_cast(short8, *(const uint4*)ap);
        }

        floatx4 acc[2];
        acc[0] = (floatx4){0.f, 0.f, 0.f, 0.f};
        acc[1] = (floatx4){0.f, 0.f, 0.f, 0.f};
#pragma unroll
        for (int kk = 0; kk < 16; kk++) {
            acc[0] = __builtin_amdgcn_mfma_f32_16x16x32_bf16(a[kk], bfr[0][kk], acc[0], 0, 0, 0);
            acc[1] = __builtin_amdgcn_mfma_f32_16x16x32_bf16(a[kk], bfr[1][kk], acc[1], 0, 0, 0);
        }

#pragma unroll
        for (int nt = 0; nt < 2; nt++) {
            int ncol = (wave * 2 + nt) * 16 + l15;
#pragma unroll
            for (int r = 0; r < 4; r++) {
                int mrow = m0 + quad * 4 + r;
                if (mrow < n) out[(size_t)mrow * F + ncol] = acc[nt][r] + bv[nt];
            }
        }
    }
}

extern "C" void kernel_launch(void* const* d_in, const int* in_sizes, int n_in,
                              void* d_out, int out_size, void* d_ws, size_t ws_size,
                              hipStream_t stream)
{
    const float* x    = (const float*)d_in[0];
    const int*   rows = (const int*)d_in[1];
    const int*   cols = (const int*)d_in[2];
    const float* vals = (const float*)d_in[3];
    const float* W    = (const float*)d_in[4];
    const float* bias = (const float*)d_in[5];

    int N = in_sizes[0] / F;
    int E = in_sizes[1];
    int NB = (N + (1 << BSH) - 1) >> BSH;       // buckets (391 for N=100k)
    float* out = (float*)d_out;

    // ---- workspace layout ----
    size_t planeElems = (size_t)N * F;                       // bf16 elems
    unsigned short* P0 = (unsigned short*)d_ws;              // 25.6 MB each
    unsigned short* P1 = P0 + planeElems;
    unsigned short* P2 = P1 + planeElems;
    unsigned short* P3 = P2 + planeElems;
    int2* edges = (int2*)(P3 + planeElems);                  // 25.6 MB
    unsigned short* Wp = (unsigned short*)(edges + E);       // 128 KB
    int* bucketTot   = (int*)(Wp + 128 * 512);               // MAXB
    int* bucketStart = bucketTot + MAXB;                     // MAXB
    int* bucketCur   = bucketStart + MAXB;                   // MAXB
    int* rowStart    = bucketCur + MAXB;                     // N
    int* rowEnd      = rowStart + N;                         // N
    uint2* tmp = (uint2*)P2;   // 25.6 MB staging, consumed before P2 written

    long long n4 = planeElems / 4;
    int castBlocks = (int)((n4 + 255) / 256);

    // ---- prep (cast + W-permute + coarse hist) ----
    hipMemsetAsync(bucketTot, 0, MAXB * sizeof(int), stream);
    prep<<<castBlocks + 512, 256, 0, stream>>>(
        (const float4*)x, (uint2*)P0, n4, W, Wp, rows, bucketTot, E, NB, castBlocks);

    // ---- CSR build: counting sort, L2-resident scatter ----
    bucket_scan<<<1, 512, 0, stream>>>(bucketTot, bucketStart, bucketCur, NB);
    pass1_scatter<<<512, 256, 0, stream>>>(rows, cols, vals, bucketCur, tmp, E, NB);
    pass2_finalize<<<NB, 256, 0, stream>>>(tmp, bucketStart, bucketCur,
                                           rowStart, rowEnd, edges, N);

    // ---- Chebyshev recurrence ----
    int spmmBlocks = (N + 3) / 4;
    spmm_bf16<<<spmmBlocks, 256, 0, stream>>>(rowStart, rowEnd, edges, P0, nullptr, P1, 1.0f,  0.0f, N);
    spmm_bf16<<<spmmBlocks, 256, 0, stream>>>(rowStart, rowEnd, edges, P1, P0,      P2, 2.0f, -1.0f, N);
    spmm_bf16<<<spmmBlocks, 256, 0, stream>>>(rowStart, rowEnd, edges, P2, P1,      P3, 2.0f, -1.0f, N);

    // ---- fused projection: out = cheb @ Wp^T + b ----
    int nTiles = (N + 15) / 16;
    int gemmGrid = nTiles < 1536 ? nTiles : 1536;
    gemm_mfma<<<gemmGrid, 256, 0, stream>>>(P0, Wp, bias, out, N, nTiles);
}